// Round 6
// baseline (131.120 us; speedup 1.0000x reference)
//
#include <hip/hip_runtime.h>
#include <hip/hip_bf16.h>
#include <math.h>

#define N 2048
#define NC 8

// ws layout:
//   [0, 64)             : double acc[8]        (zeroed by k_prep block 0)
//   [64, 64+64K)        : float  A[8][2048]
//   [64+64K, 64+128K)   : int    lohi[8][2048] (lo | hi<<16, per ORIGINAL row)
//   [64+128K, +4)       : unsigned counter     (ticket for fused finalize)

#if __has_builtin(__builtin_amdgcn_exp2f)
__device__ __forceinline__ float fexp2(float x) { return __builtin_amdgcn_exp2f(x); }
#else
__device__ __forceinline__ float fexp2(float x) { return exp2f(x); }
#endif
#if __has_builtin(__builtin_amdgcn_logf)
__device__ __forceinline__ float flog2(float x) { return __builtin_amdgcn_logf(x); }
#else
__device__ __forceinline__ float flog2(float x) { return log2f(x); }
#endif

#define INV_LN2 1.4426950408889634f
#define LN2_D   0.6931471805599453
#define CLAMP2  (-144.26950408889634f)   /* -100/ln2 : clamp in log2 domain */

// ---------------- Kernel 1: fused A-sum + counting-rank GT + acc zeroing ------
// blocks [0,256):   A[j] = sum_i |s_j - s_i|   (col = b>>5, 32 chunks of 64 j)
// blocks [256,512): counting-rank windows      (col = b2>>5, 32 chunks of 64 j)
__global__ __launch_bounds__(256) void k_prep(const float* __restrict__ logits,
                                              const float* __restrict__ dur,
                                              const int* __restrict__ ev,
                                              float* __restrict__ A,
                                              int* __restrict__ lohi,
                                              double* __restrict__ acc,
                                              unsigned* __restrict__ counter) {
    __shared__ float s[N];                   // 8 KB   (asum)
    __shared__ double part[256];             // 2 KB   (asum)
    __shared__ unsigned long long keys[N];   // 16 KB  (sortgt)
    __shared__ int pr[256], pv[256];         // 2 KB   (sortgt)

    int b = blockIdx.x;
    int tid = threadIdx.x;

    if (b == 0) {  // zero accumulators + ticket for k_bce (stream-ordered before k_bce)
        if (tid < 8) acc[tid] = 0.0;
        else if (tid == 8) counter[0] = 0u;
    }

    if (b < 256) {
        // ---- A-sum ----
        int col = b >> 5, chunk = b & 31;
        for (int k = 0; k < N / 256; ++k) {
            int i = tid + k * 256;
            s[i] = logits[i * NC + col];
        }
        __syncthreads();
        int jl = tid & 63, slice = tid >> 6;
        int j = chunk * 64 + jl;
        float sj = s[j];
        int base = slice * 512;
        double a0 = 0.0, a1 = 0.0, a2 = 0.0, a3 = 0.0;
        #pragma unroll 2
        for (int i = 0; i < 512; i += 4) {
            a0 += (double)fabsf(sj - s[base + i]);
            a1 += (double)fabsf(sj - s[base + i + 1]);
            a2 += (double)fabsf(sj - s[base + i + 2]);
            a3 += (double)fabsf(sj - s[base + i + 3]);
        }
        part[tid] = (a0 + a1) + (a2 + a3);
        __syncthreads();
        if (tid < 64) {
            double v = ((part[tid] + part[tid + 64]) + part[tid + 128]) + part[tid + 192];
            A[col * N + j] = (float)v;
        }
    } else {
        // ---- counting-rank GT windows ----
        // key = (dur_bits<<32)|(i<<1)|e : ascending u64 == stable ascending by d
        int b2 = b - 256;
        int col = b2 >> 5, chunk = b2 & 31;
        for (int k = 0; k < N / 256; ++k) {
            int i = tid + k * 256;
            unsigned int db = __float_as_uint(dur[i * NC + col]);  // dur in [0,1)
            int e = ev[i * NC + col];
            keys[i] = ((unsigned long long)db << 32) | (unsigned int)((i << 1) | e);
        }
        __syncthreads();
        int jl = tid & 63, slice = tid >> 6;
        int j = chunk * 64 + jl;
        unsigned long long kj = keys[j];
        int base = slice * 512;
        int rank = 0, evlt = 0;
        #pragma unroll 4
        for (int i = 0; i < 512; ++i) {
            unsigned long long ki = keys[base + i];
            int lt = (ki < kj) ? 1 : 0;
            rank += lt;
            evlt += lt & (int)(ki & 1ull);
        }
        pr[tid] = rank;
        pv[tid] = evlt;
        __syncthreads();
        if (tid < 64) {
            int r = ((pr[tid] + pr[tid + 64]) + pr[tid + 128]) + pr[tid + 192];
            int v = ((pv[tid] + pv[tid + 64]) + pv[tid + 128]) + pv[tid + 192];
            int e = (int)(kj & 1ull);
            int hi = e ? (r + 1) : N;
            lohi[col * N + j] = v | (hi << 16);
        }
    }
}

// ---------------- Kernel 2: softmax+BCE, register-cached, 1024-thread blocks --
// Per lane: cache 32 (s/ln2, A/ln2) pairs in regs ONCE; recompute
// tm = fma(scale, sv, -(av+m)) per pass (fma+add < ds_read_b64, zero latency).
// With C2 = CLAMP2 + L2:
//   l1 = max(log2(S-e), C2) - L2 ;  lp - l1 = max(tm,C2) - max(log2(S-e),C2)
//   row_sum = ln2 * (sum max(log2(S-e),C2) - 2048*L2 + y * sum_window(mx1-mx2))
// 1024-thread blocks (16 waves): >=4 waves/SIMD resident even at 1 block/CU
// (r5: 256-thread blocks showed ~1 block/CU resident, VALUBusy 29%).
// NOTE: no min-waves clamp in launch_bounds (r3/r4: clamp => wholesale spill).
__global__ __launch_bounds__(1024) void k_bce(const float* __restrict__ logits,
                                              const float* __restrict__ A,
                                              const int* __restrict__ lohi,
                                              double* __restrict__ acc,
                                              unsigned* __restrict__ counter,
                                              float* __restrict__ out) {
    int col = blockIdx.x >> 6;   // 0..7
    int rg  = blockIdx.x & 63;   // 0..63 (32 rows each)
    __shared__ float2 sa[N];     // {s/ln2, A/ln2}
    __shared__ double bsum[16];
    int tid = threadIdx.x;
    #pragma unroll
    for (int k = 0; k < 2; ++k) {
        int i = tid + k * 1024;
        sa[i] = make_float2(logits[i * NC + col] * INV_LN2,
                            A[col * N + i] * INV_LN2);
    }
    __syncthreads();

    int wave = tid >> 6, lane = tid & 63;

    // one-time LDS -> register cache (the ONLY per-wave LDS reads)
    float sv[32], av[32];
    #pragma unroll
    for (int k = 0; k < 32; ++k) {
        float2 v = sa[lane + (k << 6)];
        sv[k] = v.x;
        av[k] = v.y;
    }

    double rsum = 0.0;

    for (int rep = 0; rep < 2; ++rep) {
        int row = rg * 32 + wave * 2 + rep;
        float scale = (float)(N - 1 - 2 * row);

        // pass 1: row max of t = scale*sv - av, dual chains
        float m0 = -INFINITY, m1 = -INFINITY;
        #pragma unroll
        for (int k = 0; k < 32; k += 2) {
            m0 = fmaxf(m0, fmaf(scale, sv[k], -av[k]));
            m1 = fmaxf(m1, fmaf(scale, sv[k + 1], -av[k + 1]));
        }
        float m = fmaxf(m0, m1);
        #pragma unroll
        for (int off = 32; off > 0; off >>= 1)
            m = fmaxf(m, __shfl_xor(m, off, 64));

        // pass 2: S = sum 2^(t-m), dual f32 chains
        float se0 = 0.0f, se1 = 0.0f;
        #pragma unroll
        for (int k = 0; k < 32; k += 2) {
            se0 += fexp2(fmaf(scale, sv[k], -(av[k] + m)));
            se1 += fexp2(fmaf(scale, sv[k + 1], -(av[k + 1] + m)));
        }
        float se = se0 + se1;
        #pragma unroll
        for (int off = 32; off > 0; off >>= 1)
            se += __shfl_xor(se, off, 64);
        float S  = se;
        float L2 = flog2(S);
        float C2 = CLAMP2 + L2;   // clamp threshold in (t-m) log2 domain

        int lh = lohi[col * N + row];
        int lo = lh & 0xffff, hi = (lh >> 16) & 0xffff;
        unsigned wlen = (unsigned)(hi - lo);

        // pass 3: a1 = sum max(log2(S-e),C2) ; a2 = sum_window (mx1 - mx2)
        float a10 = 0.0f, a11 = 0.0f, a20 = 0.0f, a21 = 0.0f;
        #pragma unroll
        for (int k = 0; k < 32; k += 2) {
            {
                float tm  = fmaf(scale, sv[k], -(av[k] + m));
                float e   = fexp2(tm);
                float mx2 = fmaxf(flog2(S - e), C2);   // S >= e: sum of positives
                a10 += mx2;
                int j = lane + (k << 6);
                float w = ((unsigned)(j - lo) < wlen)
                            ? (fmaxf(tm, C2) - mx2) : 0.0f;
                a20 += w;
            }
            {
                float tm  = fmaf(scale, sv[k + 1], -(av[k + 1] + m));
                float e   = fexp2(tm);
                float mx2 = fmaxf(flog2(S - e), C2);
                a11 += mx2;
                int j = lane + ((k + 1) << 6);
                float w = ((unsigned)(j - lo) < wlen)
                            ? (fmaxf(tm, C2) - mx2) : 0.0f;
                a21 += w;
            }
        }
        float a1 = a10 + a11, a2 = a20 + a21;
        #pragma unroll
        for (int off = 32; off > 0; off >>= 1) {
            a1 += __shfl_xor(a1, off, 64);
            a2 += __shfl_xor(a2, off, 64);
        }
        float y = 1.0f / (float)(hi - lo);
        rsum += LN2_D * ((double)a1 - 2048.0 * (double)L2
                         + (double)y * (double)a2);
    }

    // block combine -> 1 atomic/block -> ticket finalize in last block
    if (lane == 0) bsum[wave] = rsum;
    __syncthreads();
    if (tid == 0) {
        double tot = 0.0;
        #pragma unroll
        for (int w = 0; w < 16; ++w) tot += bsum[w];
        atomicAdd(&acc[col], tot);
        __threadfence();
        unsigned old = atomicAdd(counter, 1u);
        if (old == (unsigned)(NC * 64 - 1)) {  // last block: masked mean
            __threadfence();
            float ssum = 0.0f;
            int cnt = 0;
            for (int c = 0; c < NC; ++c) {
                double av2 = atomicAdd(&acc[c], 0.0);  // device-scope coherent read
                float lc = (float)(-av2 / ((double)N * (double)N));
                if (lc > 0.0f) { ssum += lc; cnt++; }
            }
            out[0] = ssum / (float)(cnt > 0 ? cnt : 1);
        }
    }
}

extern "C" void kernel_launch(void* const* d_in, const int* in_sizes, int n_in,
                              void* d_out, int out_size, void* d_ws, size_t ws_size,
                              hipStream_t stream) {
    const float* logits    = (const float*)d_in[0];
    const int*   events    = (const int*)d_in[1];
    const float* durations = (const float*)d_in[2];
    float* out = (float*)d_out;

    char* ws = (char*)d_ws;
    double*   acc     = (double*)ws;
    float*    A       = (float*)(ws + 64);
    int*      lohi    = (int*)(ws + 64 + (size_t)NC * N * sizeof(float));
    unsigned* counter = (unsigned*)(ws + 64 + 2 * (size_t)NC * N * sizeof(float));

    k_prep<<<dim3(512), 256, 0, stream>>>(logits, durations, events, A, lohi, acc, counter);
    k_bce<<<dim3(NC * 64), 1024, 0, stream>>>(logits, A, lohi, acc, counter, out);
}

// Round 7
// 120.519 us; speedup vs baseline: 1.0880x; 1.0880x over previous
//
#include <hip/hip_runtime.h>
#include <hip/hip_bf16.h>
#include <math.h>

#define N 2048
#define NC 8

// ws layout:
//   [0, 64)             : double acc[8]        (zeroed by k_prep block 0)
//   [64, 64+64K)        : float  A[8][2048]
//   [64+64K, 64+128K)   : int    lohi[8][2048] (lo | hi<<16, per ORIGINAL row)
//   [64+128K, +4)       : unsigned counter     (ticket for fused finalize)

#if __has_builtin(__builtin_amdgcn_exp2f)
__device__ __forceinline__ float fexp2(float x) { return __builtin_amdgcn_exp2f(x); }
#else
__device__ __forceinline__ float fexp2(float x) { return exp2f(x); }
#endif
#if __has_builtin(__builtin_amdgcn_logf)
__device__ __forceinline__ float flog2(float x) { return __builtin_amdgcn_logf(x); }
#else
__device__ __forceinline__ float flog2(float x) { return log2f(x); }
#endif

#define INV_LN2 1.4426950408889634f
#define LN2_D   0.6931471805599453
#define CLAMP2  (-144.26950408889634f)   /* -100/ln2 : clamp in log2 domain */

// ---------------- Kernel 1: fused A-sum + counting-rank GT + acc zeroing ------
// blocks [0,256):   A[j] = sum_i |s_j - s_i|   (col = b>>5, 32 chunks of 64 j)
// blocks [256,512): counting-rank windows      (col = b2>>5, 32 chunks of 64 j)
__global__ __launch_bounds__(256) void k_prep(const float* __restrict__ logits,
                                              const float* __restrict__ dur,
                                              const int* __restrict__ ev,
                                              float* __restrict__ A,
                                              int* __restrict__ lohi,
                                              double* __restrict__ acc,
                                              unsigned* __restrict__ counter) {
    __shared__ float s[N];                   // 8 KB   (asum)
    __shared__ double part[256];             // 2 KB   (asum)
    __shared__ unsigned long long keys[N];   // 16 KB  (sortgt)
    __shared__ int pr[256], pv[256];         // 2 KB   (sortgt)

    int b = blockIdx.x;
    int tid = threadIdx.x;

    if (b == 0) {  // zero accumulators + ticket for k_bce (stream-ordered before k_bce)
        if (tid < 8) acc[tid] = 0.0;
        else if (tid == 8) counter[0] = 0u;
    }

    if (b < 256) {
        // ---- A-sum ----
        int col = b >> 5, chunk = b & 31;
        for (int k = 0; k < N / 256; ++k) {
            int i = tid + k * 256;
            s[i] = logits[i * NC + col];
        }
        __syncthreads();
        int jl = tid & 63, slice = tid >> 6;
        int j = chunk * 64 + jl;
        float sj = s[j];
        int base = slice * 512;
        double a0 = 0.0, a1 = 0.0, a2 = 0.0, a3 = 0.0;
        #pragma unroll 2
        for (int i = 0; i < 512; i += 4) {
            a0 += (double)fabsf(sj - s[base + i]);
            a1 += (double)fabsf(sj - s[base + i + 1]);
            a2 += (double)fabsf(sj - s[base + i + 2]);
            a3 += (double)fabsf(sj - s[base + i + 3]);
        }
        part[tid] = (a0 + a1) + (a2 + a3);
        __syncthreads();
        if (tid < 64) {
            double v = ((part[tid] + part[tid + 64]) + part[tid + 128]) + part[tid + 192];
            A[col * N + j] = (float)v;
        }
    } else {
        // ---- counting-rank GT windows ----
        // key = (dur_bits<<32)|(i<<1)|e : ascending u64 == stable ascending by d
        int b2 = b - 256;
        int col = b2 >> 5, chunk = b2 & 31;
        for (int k = 0; k < N / 256; ++k) {
            int i = tid + k * 256;
            unsigned int db = __float_as_uint(dur[i * NC + col]);  // dur in [0,1)
            int e = ev[i * NC + col];
            keys[i] = ((unsigned long long)db << 32) | (unsigned int)((i << 1) | e);
        }
        __syncthreads();
        int jl = tid & 63, slice = tid >> 6;
        int j = chunk * 64 + jl;
        unsigned long long kj = keys[j];
        int base = slice * 512;
        int rank = 0, evlt = 0;
        #pragma unroll 4
        for (int i = 0; i < 512; ++i) {
            unsigned long long ki = keys[base + i];
            int lt = (ki < kj) ? 1 : 0;
            rank += lt;
            evlt += lt & (int)(ki & 1ull);
        }
        pr[tid] = rank;
        pv[tid] = evlt;
        __syncthreads();
        if (tid < 64) {
            int r = ((pr[tid] + pr[tid + 64]) + pr[tid + 128]) + pr[tid + 192];
            int v = ((pv[tid] + pv[tid + 64]) + pv[tid + 128]) + pv[tid + 192];
            int e = (int)(kj & 1ull);
            int hi = e ? (r + 1) : N;
            lohi[col * N + j] = v | (hi << 16);
        }
    }
}

// ---------------- Kernel 2: softmax+BCE, 2-row interleave, LDS=16384 ----------
// Per lane: cache 32 (s/ln2, A/ln2) pairs in regs once. Each wave computes TWO
// rows simultaneously (independent chains => ILP-2 on every shuffle-reduce and
// transcendental chain). LDS held to exactly 16384 B by unioning the 32-B block
// reduction buffer into the staging array (r2: LDS 16384 -> occupancy 58%;
// r5: LDS 16896 -> occupancy 13.5%, latency-bound at VALUBusy 29%).
// NOTE: plain __launch_bounds__(256) ONLY — any min-waves clamp (r3/r4) or
// 1024-thread block (r6) collapses the VGPR budget and spills the reg cache.
__global__ __launch_bounds__(256) void k_bce(const float* __restrict__ logits,
                                             const float* __restrict__ A,
                                             const int* __restrict__ lohi,
                                             double* __restrict__ acc,
                                             unsigned* __restrict__ counter,
                                             float* __restrict__ out) {
    int col = blockIdx.x >> 8;   // 0..7
    int rg  = blockIdx.x & 255;  // 0..255 (8 rows each)
    __shared__ union SU {
        float2 sa[N];            // {s/ln2, A/ln2} — read only before 2nd barrier
        double bsum[4];          // reused after compute (aliases sa[0..3])
    } u;                         // exactly 16384 B
    int tid = threadIdx.x;
    int wave = tid >> 6, lane = tid & 63;

    #pragma unroll
    for (int k = 0; k < 8; ++k) {
        int i = tid + (k << 8);
        u.sa[i] = make_float2(logits[i * NC + col] * INV_LN2,
                              A[col * N + i] * INV_LN2);
    }
    __syncthreads();

    // one-time LDS -> register cache
    float sv[32], av[32];
    #pragma unroll
    for (int k = 0; k < 32; ++k) {
        float2 v = u.sa[lane + (k << 6)];
        sv[k] = v.x;
        av[k] = v.y;
    }
    __syncthreads();   // sa dead from here; u.bsum may be written below

    int rowa = (rg << 3) + (wave << 1);
    int rowb = rowa + 1;
    float sca = (float)(N - 1 - 2 * rowa);
    float scb = (float)(N - 1 - 2 * rowb);

    // pass 1: row maxes, two interleaved chains
    float ma = -INFINITY, mb = -INFINITY;
    #pragma unroll
    for (int k = 0; k < 32; ++k) {
        ma = fmaxf(ma, fmaf(sca, sv[k], -av[k]));
        mb = fmaxf(mb, fmaf(scb, sv[k], -av[k]));
    }
    #pragma unroll
    for (int off = 32; off > 0; off >>= 1) {
        ma = fmaxf(ma, __shfl_xor(ma, off, 64));
        mb = fmaxf(mb, __shfl_xor(mb, off, 64));
    }

    // pass 2: S = sum 2^(t-m), two interleaved chains
    float sea = 0.0f, seb = 0.0f;
    #pragma unroll
    for (int k = 0; k < 32; ++k) {
        sea += fexp2(fmaf(sca, sv[k], -(av[k] + ma)));
        seb += fexp2(fmaf(scb, sv[k], -(av[k] + mb)));
    }
    #pragma unroll
    for (int off = 32; off > 0; off >>= 1) {
        sea += __shfl_xor(sea, off, 64);
        seb += __shfl_xor(seb, off, 64);
    }
    float Sa = sea, Sb = seb;
    float La = flog2(Sa), Lb = flog2(Sb);
    float C2a = CLAMP2 + La, C2b = CLAMP2 + Lb;

    int lha = lohi[col * N + rowa];
    int lhb = lohi[col * N + rowb];
    int loa = lha & 0xffff, hia = (lha >> 16) & 0xffff;
    int lob = lhb & 0xffff, hib = (lhb >> 16) & 0xffff;
    unsigned wla = (unsigned)(hia - loa), wlb = (unsigned)(hib - lob);

    // pass 3: a1 = sum max(log2(S-e),C2) ; a2 = sum_window (max(tm,C2) - mx2)
    float a1a = 0.0f, a2a = 0.0f, a1b = 0.0f, a2b = 0.0f;
    #pragma unroll
    for (int k = 0; k < 32; ++k) {
        int j = lane + (k << 6);
        {
            float tm  = fmaf(sca, sv[k], -(av[k] + ma));
            float e   = fexp2(tm);
            float mx2 = fmaxf(flog2(Sa - e), C2a);   // S >= e: sum of positives
            a1a += mx2;
            float w = ((unsigned)(j - loa) < wla) ? (fmaxf(tm, C2a) - mx2) : 0.0f;
            a2a += w;
        }
        {
            float tm  = fmaf(scb, sv[k], -(av[k] + mb));
            float e   = fexp2(tm);
            float mx2 = fmaxf(flog2(Sb - e), C2b);
            a1b += mx2;
            float w = ((unsigned)(j - lob) < wlb) ? (fmaxf(tm, C2b) - mx2) : 0.0f;
            a2b += w;
        }
    }
    #pragma unroll
    for (int off = 32; off > 0; off >>= 1) {
        a1a += __shfl_xor(a1a, off, 64);
        a2a += __shfl_xor(a2a, off, 64);
        a1b += __shfl_xor(a1b, off, 64);
        a2b += __shfl_xor(a2b, off, 64);
    }
    float ya = 1.0f / (float)(hia - loa);
    float yb = 1.0f / (float)(hib - lob);
    double rsum = LN2_D * ((double)a1a - 2048.0 * (double)La + (double)ya * (double)a2a)
                + LN2_D * ((double)a1b - 2048.0 * (double)Lb + (double)yb * (double)a2b);

    // block combine -> 1 atomic/block -> ticket finalize in last block
    if (lane == 0) u.bsum[wave] = rsum;
    __syncthreads();
    if (tid == 0) {
        double tot = (u.bsum[0] + u.bsum[1]) + (u.bsum[2] + u.bsum[3]);
        atomicAdd(&acc[col], tot);
        __threadfence();
        unsigned old = atomicAdd(counter, 1u);
        if (old == (unsigned)(NC * 256 - 1)) {  // last block: masked mean
            __threadfence();
            float ssum = 0.0f;
            int cnt = 0;
            for (int c = 0; c < NC; ++c) {
                double av2 = atomicAdd(&acc[c], 0.0);  // device-scope coherent read
                float lc = (float)(-av2 / ((double)N * (double)N));
                if (lc > 0.0f) { ssum += lc; cnt++; }
            }
            out[0] = ssum / (float)(cnt > 0 ? cnt : 1);
        }
    }
}

extern "C" void kernel_launch(void* const* d_in, const int* in_sizes, int n_in,
                              void* d_out, int out_size, void* d_ws, size_t ws_size,
                              hipStream_t stream) {
    const float* logits    = (const float*)d_in[0];
    const int*   events    = (const int*)d_in[1];
    const float* durations = (const float*)d_in[2];
    float* out = (float*)d_out;

    char* ws = (char*)d_ws;
    double*   acc     = (double*)ws;
    float*    A       = (float*)(ws + 64);
    int*      lohi    = (int*)(ws + 64 + (size_t)NC * N * sizeof(float));
    unsigned* counter = (unsigned*)(ws + 64 + 2 * (size_t)NC * N * sizeof(float));

    k_prep<<<dim3(512), 256, 0, stream>>>(logits, durations, events, A, lohi, acc, counter);
    k_bce<<<dim3(NC * 256), 256, 0, stream>>>(logits, A, lohi, acc, counter, out);
}